// Round 2
// baseline (329.204 us; speedup 1.0000x reference)
//
#include <hip/hip_runtime.h>
#include <math.h>

#define CROP 96
#define WIN 11
#define OUT 86      // CROP - WIN + 1
#define IMH 1080
#define IMW 1920
#define NB 8        // row-bands per (sample, channel)
#define BROWS 11    // output rows per band (last band has 9 valid)
#define NQ 3        // row-quads per band (12 padded rows)

// vcol layout: [col 0..95][map 0..4][row 0..11] floats
// float4 view: index = col*15 + map*3 + quad   (all 16B-aligned)

__global__ __launch_bounds__(256, 4) void ssim_stage_kernel(
    const float* __restrict__ img,
    const float* __restrict__ imgr,
    const int* __restrict__ target,
    float* __restrict__ block_sums)
{
    __shared__ float vcol[CROP * 5 * 12];   // 23040 B
    __shared__ float red[256];

    const int blk  = blockIdx.x;
    const int s    = blk / (3 * NB);
    const int rem  = blk - s * (3 * NB);
    const int c    = rem / NB;
    const int band = rem - c * NB;
    const int r0   = band * BROWS;

    const int xmin = target[s * 5 + 0];
    const int ymin = target[s * 5 + 1];

    const float* __restrict__ pa = img  + (size_t)c * IMH * IMW;
    const float* __restrict__ pb = imgr + (size_t)c * IMH * IMW;

    const int tid = threadIdx.x;

    // gaussian weights (f32, matches reference)
    float gw[WIN];
    {
        float sum = 0.f;
        #pragma unroll
        for (int k = 0; k < WIN; ++k) {
            const float cc = (float)k - (float)(WIN - 1) * 0.5f;
            gw[k] = expf(-(cc * cc) / (2.0f * 1.5f * 1.5f));
            sum += gw[k];
        }
        const float inv = 1.0f / sum;
        #pragma unroll
        for (int k = 0; k < WIN; ++k) gw[k] *= inv;
    }

    // ---- stage 1: vertical 11-tap conv, 4 rows per thread-task, global -> LDS ----
    for (int t = tid; t < CROP * NQ; t += 256) {
        const int col  = t % CROP;          // consecutive lanes -> consecutive cols
        const int quad = t / CROP;
        const int gx   = xmin + col;
        const int gy0  = ymin + r0 + quad * 4;

        float va[4]  = {0.f,0.f,0.f,0.f};
        float vb[4]  = {0.f,0.f,0.f,0.f};
        float vaa[4] = {0.f,0.f,0.f,0.f};
        float vbb[4] = {0.f,0.f,0.f,0.f};
        float vab[4] = {0.f,0.f,0.f,0.f};

        #pragma unroll
        for (int tt = 0; tt < 14; ++tt) {   // 14-tap window covers 4 rows of 11-tap conv
            int gy = gy0 + tt;
            gy = gy > (IMH - 1) ? (IMH - 1) : gy;   // pad rows clamp (only feed invalid outputs)
            const float a  = pa[(size_t)gy * IMW + gx];
            const float b  = pb[(size_t)gy * IMW + gx];
            const float aa = a * a;
            const float bb = b * b;
            const float ab = a * b;
            #pragma unroll
            for (int j = 0; j < 4; ++j) {
                const int k = tt - j;
                if (k >= 0 && k < WIN) {
                    const float w = gw[k];
                    va[j]  += w * a;
                    vb[j]  += w * b;
                    vaa[j] += w * aa;
                    vbb[j] += w * bb;
                    vab[j] += w * ab;
                }
            }
        }

        const int base4 = col * 15 + quad;  // float4 index, + map*3
        float4* v4 = reinterpret_cast<float4*>(vcol);
        v4[base4 + 0*3] = make_float4(va[0],  va[1],  va[2],  va[3]);
        v4[base4 + 1*3] = make_float4(vb[0],  vb[1],  vb[2],  vb[3]);
        v4[base4 + 2*3] = make_float4(vaa[0], vaa[1], vaa[2], vaa[3]);
        v4[base4 + 3*3] = make_float4(vbb[0], vbb[1], vbb[2], vbb[3]);
        v4[base4 + 4*3] = make_float4(vab[0], vab[1], vab[2], vab[3]);
    }

    __syncthreads();

    // ---- stage 2: horizontal 11-tap conv + SSIM, 4 rows (one quad) per thread-task ----
    const float C1 = 6.5025f;
    const float C2 = 58.5225f;
    int rmax = OUT - r0;                    // valid rows this band
    if (rmax > BROWS) rmax = BROWS;

    float acc = 0.f;
    const float4* v4 = reinterpret_cast<const float4*>(vcol);

    for (int t = tid; t < OUT * NQ; t += 256) {
        const int x    = t % OUT;           // consecutive lanes -> consecutive x
        const int quad = t / OUT;

        float m1[4]  = {0.f,0.f,0.f,0.f};
        float m2[4]  = {0.f,0.f,0.f,0.f};
        float eaa[4] = {0.f,0.f,0.f,0.f};
        float ebb[4] = {0.f,0.f,0.f,0.f};
        float eab[4] = {0.f,0.f,0.f,0.f};

        #pragma unroll
        for (int k = 0; k < WIN; ++k) {
            const float w = gw[k];
            const int b4 = (x + k) * 15 + quad;
            const float4 pva  = v4[b4 + 0*3];
            const float4 pvb  = v4[b4 + 1*3];
            const float4 pvaa = v4[b4 + 2*3];
            const float4 pvbb = v4[b4 + 3*3];
            const float4 pvab = v4[b4 + 4*3];
            m1[0] += w * pva.x;  m1[1] += w * pva.y;  m1[2] += w * pva.z;  m1[3] += w * pva.w;
            m2[0] += w * pvb.x;  m2[1] += w * pvb.y;  m2[2] += w * pvb.z;  m2[3] += w * pvb.w;
            eaa[0] += w * pvaa.x; eaa[1] += w * pvaa.y; eaa[2] += w * pvaa.z; eaa[3] += w * pvaa.w;
            ebb[0] += w * pvbb.x; ebb[1] += w * pvbb.y; ebb[2] += w * pvbb.z; ebb[3] += w * pvbb.w;
            eab[0] += w * pvab.x; eab[1] += w * pvab.y; eab[2] += w * pvab.z; eab[3] += w * pvab.w;
        }

        #pragma unroll
        for (int j = 0; j < 4; ++j) {
            const int vrow = quad * 4 + j;
            const float mu1  = m1[j];
            const float mu2  = m2[j];
            const float mu1s = mu1 * mu1;
            const float mu2s = mu2 * mu2;
            const float mu12 = mu1 * mu2;
            const float s1   = eaa[j] - mu1s;
            const float s2   = ebb[j] - mu2s;
            const float s12  = eab[j] - mu12;
            const float num  = (2.f * mu12 + C1) * (2.f * s12 + C2);
            const float den  = (mu1s + mu2s + C1) * (s1 + s2 + C2);
            const float val  = num * __builtin_amdgcn_rcpf(den);
            if (vrow < rmax) acc += val;
        }
    }

    // ---- deterministic block reduction ----
    red[tid] = acc;
    __syncthreads();
    #pragma unroll
    for (int off = 128; off > 0; off >>= 1) {
        if (tid < off) red[tid] += red[tid + off];
        __syncthreads();
    }
    if (tid == 0) block_sums[blk] = red[0];
}

__global__ __launch_bounds__(256) void ssim_finalize_kernel(
    const float* __restrict__ block_sums,
    float* __restrict__ out,
    int nblk,
    float inv_npix)
{
    __shared__ float red[256];
    const int tid = threadIdx.x;
    float s = 0.f;
    for (int i = tid; i < nblk; i += 256) s += block_sums[i];
    red[tid] = s;
    __syncthreads();
    #pragma unroll
    for (int off = 128; off > 0; off >>= 1) {
        if (tid < off) red[tid] += red[tid + off];
        __syncthreads();
    }
    if (tid == 0) {
        const float mean = red[0] * inv_npix;
        out[0] = 5.0f * (1.0f - mean);
    }
}

extern "C" void kernel_launch(void* const* d_in, const int* in_sizes, int n_in,
                              void* d_out, int out_size, void* d_ws, size_t ws_size,
                              hipStream_t stream)
{
    const float* img  = (const float*)d_in[0];
    const float* imgr = (const float*)d_in[1];
    const int*   tgt  = (const int*)d_in[2];
    const int N = in_sizes[2] / 5;
    const int nblk = 3 * N * NB;

    float* block_sums = (float*)d_ws;
    const float inv_npix = 1.0f / ((float)(3 * N) * (float)(OUT * OUT));

    ssim_stage_kernel<<<nblk, 256, 0, stream>>>(img, imgr, tgt, block_sums);
    ssim_finalize_kernel<<<1, 256, 0, stream>>>(block_sums, (float*)d_out, nblk, inv_npix);
}

// Round 3
// 56.219 us; speedup vs baseline: 5.8557x; 5.8557x over previous
//
#include <hip/hip_runtime.h>
#include <math.h>

#define CROP 96
#define WIN 11
#define OUT 86          // CROP - WIN + 1
#define IMH 1080
#define IMW 1920
#define BAND 32         // output rows per band
#define NBAND 3         // ceil(86/32)
#define AROWS (BAND + WIN - 1)   // 42 input rows per band
#define XQ 22           // x-quads of 4 out-cols (88 slots >= 86)
#define PADX (XQ * 4)   // 88 floats per map-row

// LDS layout: hrow[input_row 0..41][map 0..4][88 floats]
// float4 view: idx = (row*5 + m)*22 + xq

__global__ __launch_bounds__(256) void ssim_kernel(
    const float* __restrict__ img,
    const float* __restrict__ imgr,
    const int* __restrict__ target,
    float* __restrict__ block_sums)
{
    __shared__ float4 hrow4[AROWS * 5 * XQ];   // 73920 B
    __shared__ float red[256];

    const int blk  = blockIdx.x;
    const int s    = blk / (3 * NBAND);
    const int rem  = blk - s * (3 * NBAND);
    const int c    = rem / NBAND;
    const int band = rem - c * NBAND;
    const int r0out = band * BAND;             // first output row of this band

    const int xmin = target[s * 5 + 0];
    const int ymin = target[s * 5 + 1];

    const float* __restrict__ pa = img  + (size_t)c * IMH * IMW;
    const float* __restrict__ pb = imgr + (size_t)c * IMH * IMW;

    const int tid = threadIdx.x;

    // gaussian weights (f32, matches reference)
    float gw[WIN];
    {
        float sum = 0.f;
        #pragma unroll
        for (int k = 0; k < WIN; ++k) {
            const float cc = (float)k - (float)(WIN - 1) * 0.5f;
            gw[k] = expf(-(cc * cc) / (2.0f * 1.5f * 1.5f));
            sum += gw[k];
        }
        const float inv = 1.0f / sum;
        #pragma unroll
        for (int k = 0; k < WIN; ++k) gw[k] *= inv;
    }

    // ---- phase A: horizontal 11-tap conv, 4 out-cols per task, global -> LDS ----
    for (int t = tid; t < AROWS * XQ; t += 256) {
        const int xq = t % XQ;                 // consecutive lanes -> consecutive xq
        const int ar = t / XQ;
        int y = r0out + ar;
        y = y > (CROP - 1) ? (CROP - 1) : y;   // clamp pad rows (feed only masked outputs)
        const size_t rowoff = (size_t)(ymin + y) * IMW + (size_t)(xmin + xq * 4);
        const float* __restrict__ rowa = pa + rowoff;
        const float* __restrict__ rowb = pb + rowoff;

        float a5[5][4] = {{0.f}};
        #pragma unroll
        for (int tt = 0; tt < 14; ++tt) {      // 14-pixel window covers 4 out-cols
            const float a  = rowa[tt];
            const float b  = rowb[tt];
            const float aa = a * a;
            const float bb = b * b;
            const float ab = a * b;
            #pragma unroll
            for (int jj = 0; jj < 4; ++jj) {
                const int k = tt - jj;
                if (k >= 0 && k < WIN) {
                    const float w = gw[k];
                    a5[0][jj] += w * a;
                    a5[1][jj] += w * b;
                    a5[2][jj] += w * aa;
                    a5[3][jj] += w * bb;
                    a5[4][jj] += w * ab;
                }
            }
        }
        const int base4 = ar * 5 * XQ + xq;
        #pragma unroll
        for (int m = 0; m < 5; ++m)
            hrow4[base4 + m * XQ] = make_float4(a5[m][0], a5[m][1], a5[m][2], a5[m][3]);
    }

    __syncthreads();

    // ---- phase B: vertical 11-tap conv + SSIM, 8 out-rows per task, LDS -> regs ----
    const float C1 = 6.5025f;
    const float C2 = 58.5225f;
    const float* __restrict__ hrowF = reinterpret_cast<const float*>(hrow4);

    float acc = 0.f;
    for (int t = tid; t < OUT * 4; t += 256) { // 344 tasks
        const int x   = t % OUT;               // consecutive lanes -> consecutive x
        const int o   = t / OUT;
        const int lr0 = o * 8;                 // first local out-row of this oct
        if (r0out + lr0 >= OUT) continue;      // whole oct invalid (band 2 tail)

        float m1[8]  = {0.f}; float m2[8]  = {0.f};
        float eaa[8] = {0.f}; float ebb[8] = {0.f}; float eab[8] = {0.f};

        #pragma unroll
        for (int tt = 0; tt < 18; ++tt) {      // 18-row window covers 8 out-rows
            const int rbase = ((lr0 + tt) * 5) * PADX + x;
            const float va  = hrowF[rbase];
            const float vb  = hrowF[rbase + PADX];
            const float vaa = hrowF[rbase + 2 * PADX];
            const float vbb = hrowF[rbase + 3 * PADX];
            const float vab = hrowF[rbase + 4 * PADX];
            #pragma unroll
            for (int jj = 0; jj < 8; ++jj) {
                const int k = tt - jj;
                if (k >= 0 && k < WIN) {
                    const float w = gw[k];
                    m1[jj]  += w * va;
                    m2[jj]  += w * vb;
                    eaa[jj] += w * vaa;
                    ebb[jj] += w * vbb;
                    eab[jj] += w * vab;
                }
            }
        }

        #pragma unroll
        for (int jj = 0; jj < 8; ++jj) {
            const int grow = r0out + lr0 + jj;
            const float mu1  = m1[jj];
            const float mu2  = m2[jj];
            const float mu1s = mu1 * mu1;
            const float mu2s = mu2 * mu2;
            const float mu12 = mu1 * mu2;
            const float s1   = eaa[jj] - mu1s;
            const float s2   = ebb[jj] - mu2s;
            const float s12  = eab[jj] - mu12;
            const float num  = (2.f * mu12 + C1) * (2.f * s12 + C2);
            const float den  = (mu1s + mu2s + C1) * (s1 + s2 + C2);
            const float val  = num * __builtin_amdgcn_rcpf(den);
            if (grow < OUT) acc += val;
        }
    }

    // ---- deterministic block reduction ----
    red[tid] = acc;
    __syncthreads();
    #pragma unroll
    for (int off = 128; off > 0; off >>= 1) {
        if (tid < off) red[tid] += red[tid + off];
        __syncthreads();
    }
    if (tid == 0) block_sums[blk] = red[0];
}

__global__ __launch_bounds__(256) void ssim_finalize_kernel(
    const float* __restrict__ block_sums,
    float* __restrict__ out,
    int nblk,
    float inv_npix)
{
    __shared__ float red[256];
    const int tid = threadIdx.x;
    float s = 0.f;
    for (int i = tid; i < nblk; i += 256) s += block_sums[i];
    red[tid] = s;
    __syncthreads();
    #pragma unroll
    for (int off = 128; off > 0; off >>= 1) {
        if (tid < off) red[tid] += red[tid + off];
        __syncthreads();
    }
    if (tid == 0) {
        const float mean = red[0] * inv_npix;
        out[0] = 5.0f * (1.0f - mean);
    }
}

extern "C" void kernel_launch(void* const* d_in, const int* in_sizes, int n_in,
                              void* d_out, int out_size, void* d_ws, size_t ws_size,
                              hipStream_t stream)
{
    const float* img  = (const float*)d_in[0];
    const float* imgr = (const float*)d_in[1];
    const int*   tgt  = (const int*)d_in[2];
    const int N = in_sizes[2] / 5;
    const int nblk = 3 * N * NBAND;

    float* block_sums = (float*)d_ws;
    const float inv_npix = 1.0f / ((float)(3 * N) * (float)(OUT * OUT));

    ssim_kernel<<<nblk, 256, 0, stream>>>(img, imgr, tgt, block_sums);
    ssim_finalize_kernel<<<1, 256, 0, stream>>>(block_sums, (float*)d_out, nblk, inv_npix);
}

// Round 4
// 45.489 us; speedup vs baseline: 7.2370x; 1.2359x over previous
//
#include <hip/hip_runtime.h>
#include <math.h>

#define CROP 96
#define WIN 11
#define OUT 86          // CROP - WIN + 1
#define IMH 1080
#define IMW 1920
#define CH 16           // output rows per chunk
#define NCH 6           // ceil(86/16)
#define STRD 92         // padded floats per (row,map) lane in LDS

// LDS: hbuf[(row&31)][map 0..3][STRD], maps = E[p],E[q],E[p^2],E[q^2] (horiz conv)

__global__ __launch_bounds__(256) void ssim_kernel(
    const float* __restrict__ img,
    const float* __restrict__ imgr,
    const int* __restrict__ target,
    float* __restrict__ block_sums)
{
    __shared__ __align__(16) float hbuf[32 * 4 * STRD];  // 47104 B
    __shared__ float red[256];

    const int blk = blockIdx.x;          // 0 .. 3N-1
    const int s   = blk / 3;
    const int c   = blk % 3;

    const int xmin = target[s * 5 + 0];
    const int ymin = target[s * 5 + 1];

    const size_t cbase = (size_t)c * (IMH * IMW) + (size_t)ymin * IMW + (size_t)xmin;
    const float* __restrict__ pa = img  + cbase;
    const float* __restrict__ pb = imgr + cbase;

    const int tid = threadIdx.x;

    // gaussian weights (f32, matches reference)
    float gw[WIN];
    {
        float sum = 0.f;
        #pragma unroll
        for (int k = 0; k < WIN; ++k) {
            const float cc = (float)k - (float)(WIN - 1) * 0.5f;
            gw[k] = expf(-(cc * cc) / (2.0f * 1.5f * 1.5f));
            sum += gw[k];
        }
        const float inv = 1.0f / sum;
        #pragma unroll
        for (int k = 0; k < WIN; ++k) gw[k] *= inv;
    }

    // ---- phase A: horizontal 11-tap conv of input rows [a0, a0+nr), 8 cols/task ----
    auto doA = [&](int a0, int nr) {
        for (int t = tid; t < nr * 11; t += 256) {
            const int g   = t % 11;              // consecutive lanes -> consecutive col groups
            const int row = a0 + t / 11;
            const int xo  = g * 8;
            const float* __restrict__ ra = pa + (size_t)row * IMW;
            const float* __restrict__ rb = pb + (size_t)row * IMW;

            float P[8] = {}, Q[8] = {}, PP[8] = {}, QQ[8] = {};
            #pragma unroll
            for (int tt = 0; tt < 18; ++tt) {    // 18-px window covers 8 out-cols
                int cx = xo + tt;
                cx = cx > (CROP - 1) ? (CROP - 1) : cx;   // only feeds unread cols 86/87
                const float a = ra[cx];
                const float b = rb[cx];
                const float p  = a + b, q = a - b;
                const float pp = p * p, qq = q * q;
                #pragma unroll
                for (int jj = 0; jj < 8; ++jj) {
                    const int k = tt - jj;
                    if (k >= 0 && k < WIN) {
                        const float w = gw[k];
                        P[jj]  += w * p;  Q[jj]  += w * q;
                        PP[jj] += w * pp; QQ[jj] += w * qq;
                    }
                }
            }
            const int hb = ((row & 31) * 4) * STRD + xo;
            *(float4*)&hbuf[hb           ] = make_float4(P[0],  P[1],  P[2],  P[3]);
            *(float4*)&hbuf[hb + 4       ] = make_float4(P[4],  P[5],  P[6],  P[7]);
            *(float4*)&hbuf[hb +   STRD  ] = make_float4(Q[0],  Q[1],  Q[2],  Q[3]);
            *(float4*)&hbuf[hb +   STRD+4] = make_float4(Q[4],  Q[5],  Q[6],  Q[7]);
            *(float4*)&hbuf[hb + 2*STRD  ] = make_float4(PP[0], PP[1], PP[2], PP[3]);
            *(float4*)&hbuf[hb + 2*STRD+4] = make_float4(PP[4], PP[5], PP[6], PP[7]);
            *(float4*)&hbuf[hb + 3*STRD  ] = make_float4(QQ[0], QQ[1], QQ[2], QQ[3]);
            *(float4*)&hbuf[hb + 3*STRD+4] = make_float4(QQ[4], QQ[5], QQ[6], QQ[7]);
        }
    };

    // prologue: input rows 0..25
    doA(0, 26);
    __syncthreads();

    const float C1 = 6.5025f;
    const float C2 = 58.5225f;
    float acc = 0.f;

    for (int ch = 0; ch < NCH; ++ch) {
        const int rbase = ch * CH;

        // ---- phase B: vertical 11-tap conv + SSIM, 8 out-rows per task ----
        for (int t = tid; t < OUT * 2; t += 256) {   // 172 tasks
            const int x  = t % OUT;                   // consecutive lanes -> consecutive x
            const int g  = t / OUT;
            const int r0 = rbase + g * 8;
            if (r0 >= OUT) continue;

            float mP[8] = {}, mQ[8] = {}, mPP[8] = {}, mQQ[8] = {};
            #pragma unroll
            for (int tt = 0; tt < 18; ++tt) {        // rows r0 .. r0+17
                const int row = r0 + tt;
                const int hb  = ((row & 31) * 4) * STRD + x;
                const float vP  = hbuf[hb];
                const float vQ  = hbuf[hb + STRD];
                const float vPP = hbuf[hb + 2 * STRD];
                const float vQQ = hbuf[hb + 3 * STRD];
                #pragma unroll
                for (int jj = 0; jj < 8; ++jj) {
                    const int k = tt - jj;
                    if (k >= 0 && k < WIN) {
                        const float w = gw[k];
                        mP[jj]  += w * vP;  mQ[jj]  += w * vQ;
                        mPP[jj] += w * vPP; mQQ[jj] += w * vQQ;
                    }
                }
            }
            #pragma unroll
            for (int jj = 0; jj < 8; ++jj) {
                if (r0 + jj < OUT) {
                    const float Psq = mP[jj] * mP[jj];
                    const float Qsq = mQ[jj] * mQ[jj];
                    const float mu12x2  = (Psq - Qsq) * 0.5f;            // 2*mu1*mu2
                    const float musqsum = (Psq + Qsq) * 0.5f;            // mu1^2+mu2^2
                    const float s12x2   = (mPP[jj] - mQQ[jj]) * 0.5f - mu12x2;  // 2*s12
                    const float ssum    = (mPP[jj] + mQQ[jj]) * 0.5f - musqsum; // s1+s2
                    const float num = (mu12x2 + C1) * (s12x2 + C2);
                    const float den = (musqsum + C1) * (ssum + C2);
                    acc += num * __builtin_amdgcn_rcpf(den);
                }
            }
        }
        __syncthreads();

        // ---- phase A: append next CH input rows ----
        const int a0 = rbase + 26;
        int nr = CROP - a0;
        nr = nr > CH ? CH : nr;
        if (nr > 0) doA(a0, nr);
        __syncthreads();
    }

    // ---- deterministic block reduction ----
    red[tid] = acc;
    __syncthreads();
    #pragma unroll
    for (int off = 128; off > 0; off >>= 1) {
        if (tid < off) red[tid] += red[tid + off];
        __syncthreads();
    }
    if (tid == 0) block_sums[blk] = red[0];
}

__global__ __launch_bounds__(256) void ssim_finalize_kernel(
    const float* __restrict__ block_sums,
    float* __restrict__ out,
    int nblk,
    float inv_npix)
{
    __shared__ float red[256];
    const int tid = threadIdx.x;
    float s = 0.f;
    for (int i = tid; i < nblk; i += 256) s += block_sums[i];
    red[tid] = s;
    __syncthreads();
    #pragma unroll
    for (int off = 128; off > 0; off >>= 1) {
        if (tid < off) red[tid] += red[tid + off];
        __syncthreads();
    }
    if (tid == 0) {
        const float mean = red[0] * inv_npix;
        out[0] = 5.0f * (1.0f - mean);
    }
}

extern "C" void kernel_launch(void* const* d_in, const int* in_sizes, int n_in,
                              void* d_out, int out_size, void* d_ws, size_t ws_size,
                              hipStream_t stream)
{
    const float* img  = (const float*)d_in[0];
    const float* imgr = (const float*)d_in[1];
    const int*   tgt  = (const int*)d_in[2];
    const int N = in_sizes[2] / 5;
    const int nblk = 3 * N;

    float* block_sums = (float*)d_ws;
    const float inv_npix = 1.0f / ((float)nblk * (float)(OUT * OUT));

    ssim_kernel<<<nblk, 256, 0, stream>>>(img, imgr, tgt, block_sums);
    ssim_finalize_kernel<<<1, 256, 0, stream>>>(block_sums, (float*)d_out, nblk, inv_npix);
}

// Round 5
// 35.109 us; speedup vs baseline: 9.3766x; 1.2956x over previous
//
#include <hip/hip_runtime.h>
#include <math.h>

#define CROP 96
#define WIN 11
#define OUT 86          // CROP - WIN + 1
#define IMH 1080
#define IMW 1920
#define CH 20           // output rows per chunk
#define NCH 5           // ceil(86/20)
#define RS 396          // words per row-slot: 11 xblocks * 36 + pad -> 12 mod 32
#define XBS 36          // words per 8-pixel x-block (8*4 + 4 pad)

// LDS: per (row,x) one float4 (P, Q, PP, QQ) = horizontal 11-tap conv of
// p=a+b, q=a-b, p^2, q^2.  word index = (row&31)*RS + (x>>3)*XBS + (x&7)*4

__global__ __launch_bounds__(256) void ssim_kernel(
    const float* __restrict__ img,
    const float* __restrict__ imgr,
    const int* __restrict__ target,
    float* __restrict__ block_sums)
{
    __shared__ __align__(16) float hbuf[32 * RS];   // 50688 B
    __shared__ float red[256];

    const int blk = blockIdx.x;          // 0 .. 3N-1
    const int s   = blk / 3;
    const int c   = blk % 3;

    const int xmin = target[s * 5 + 0];
    const int ymin = target[s * 5 + 1];

    const size_t cbase = (size_t)c * (IMH * IMW) + (size_t)ymin * IMW + (size_t)xmin;
    const float* __restrict__ pa = img  + cbase;
    const float* __restrict__ pb = imgr + cbase;

    const int tid = threadIdx.x;

    // gaussian weights (f32, matches reference)
    float gw[WIN];
    {
        float sum = 0.f;
        #pragma unroll
        for (int k = 0; k < WIN; ++k) {
            const float cc = (float)k - (float)(WIN - 1) * 0.5f;
            gw[k] = expf(-(cc * cc) / (2.0f * 1.5f * 1.5f));
            sum += gw[k];
        }
        const float inv = 1.0f / sum;
        #pragma unroll
        for (int k = 0; k < WIN; ++k) gw[k] *= inv;
    }

    // ---- phase A: horizontal 11-tap conv of input rows [a0, a0+nr), 8 cols/task ----
    auto doA = [&](int a0, int nr) {
        for (int t = tid; t < nr * 11; t += 256) {
            const int g   = t % 11;              // consecutive lanes -> consecutive col groups
            const int row = a0 + t / 11;
            const int xo  = g * 8;
            const float* __restrict__ ra = pa + (size_t)row * IMW;
            const float* __restrict__ rb = pb + (size_t)row * IMW;

            float P[8] = {}, Q[8] = {}, PP[8] = {}, QQ[8] = {};
            #pragma unroll
            for (int tt = 0; tt < 18; ++tt) {    // 18-px window covers 8 out-cols
                int cx = xo + tt;
                cx = cx > (CROP - 1) ? (CROP - 1) : cx;   // only feeds unread cols 86/87
                const float a = ra[cx];
                const float b = rb[cx];
                const float p  = a + b, q = a - b;
                const float pp = p * p, qq = q * q;
                #pragma unroll
                for (int jj = 0; jj < 8; ++jj) {
                    const int k = tt - jj;
                    if (k >= 0 && k < WIN) {
                        const float w = gw[k];
                        P[jj]  += w * p;  Q[jj]  += w * q;
                        PP[jj] += w * pp; QQ[jj] += w * qq;
                    }
                }
            }
            const int base = (row & 31) * RS + g * XBS;   // xo aligned to block
            #pragma unroll
            for (int jj = 0; jj < 8; ++jj) {
                *(float4*)&hbuf[base + jj * 4] =
                    make_float4(P[jj], Q[jj], PP[jj], QQ[jj]);
            }
        }
    };

    // prologue: input rows 0..29
    doA(0, 30);
    __syncthreads();

    const float C1 = 6.5025f;
    const float C2 = 58.5225f;
    float acc = 0.f;

    for (int ch = 0; ch < NCH; ++ch) {
        const int rbase = ch * CH;

        // ---- phase B: vertical 11-tap conv + SSIM, 4 rows x 2 cols per task ----
        for (int t = tid; t < 43 * 5; t += 256) {  // 215 tasks
            const int xp = t % 43;                  // consecutive lanes -> consecutive col-pairs
            const int rg = t / 43;
            const int r0 = rbase + rg * 4;
            if (r0 >= OUT) continue;
            const int x0 = xp * 2;

            float aP[4] = {}, aQ[4] = {}, aPP[4] = {}, aQQ[4] = {};
            float bP[4] = {}, bQ[4] = {}, bPP[4] = {}, bQQ[4] = {};

            #pragma unroll
            for (int tt = 0; tt < 14; ++tt) {      // rows r0 .. r0+13 cover 4 out-rows
                const int row = r0 + tt;
                const int wbase = (row & 31) * RS + (x0 >> 3) * XBS + (x0 & 7) * 4;
                const float4 fa = *(const float4*)&hbuf[wbase];
                const float4 fb = *(const float4*)&hbuf[wbase + 4];   // x0+1 (same block: x0 even)
                #pragma unroll
                for (int jj = 0; jj < 4; ++jj) {
                    const int k = tt - jj;
                    if (k >= 0 && k < WIN) {
                        const float w = gw[k];
                        aP[jj]  += w * fa.x; aQ[jj]  += w * fa.y;
                        aPP[jj] += w * fa.z; aQQ[jj] += w * fa.w;
                        bP[jj]  += w * fb.x; bQ[jj]  += w * fb.y;
                        bPP[jj] += w * fb.z; bQQ[jj] += w * fb.w;
                    }
                }
            }

            #pragma unroll
            for (int jj = 0; jj < 4; ++jj) {
                if (r0 + jj < OUT) {
                    {
                        const float Psq = aP[jj] * aP[jj];
                        const float Qsq = aQ[jj] * aQ[jj];
                        const float mu12x2  = (Psq - Qsq) * 0.5f;
                        const float musqsum = (Psq + Qsq) * 0.5f;
                        const float s12x2   = (aPP[jj] - aQQ[jj]) * 0.5f - mu12x2;
                        const float ssum    = (aPP[jj] + aQQ[jj]) * 0.5f - musqsum;
                        const float num = (mu12x2 + C1) * (s12x2 + C2);
                        const float den = (musqsum + C1) * (ssum + C2);
                        acc += num * __builtin_amdgcn_rcpf(den);
                    }
                    {
                        const float Psq = bP[jj] * bP[jj];
                        const float Qsq = bQ[jj] * bQ[jj];
                        const float mu12x2  = (Psq - Qsq) * 0.5f;
                        const float musqsum = (Psq + Qsq) * 0.5f;
                        const float s12x2   = (bPP[jj] - bQQ[jj]) * 0.5f - mu12x2;
                        const float ssum    = (bPP[jj] + bQQ[jj]) * 0.5f - musqsum;
                        const float num = (mu12x2 + C1) * (s12x2 + C2);
                        const float den = (musqsum + C1) * (ssum + C2);
                        acc += num * __builtin_amdgcn_rcpf(den);
                    }
                }
            }
        }
        __syncthreads();

        // ---- phase A: append next CH input rows ----
        const int a0 = 30 + ch * CH;
        int nr = CROP - a0;
        nr = nr > CH ? CH : nr;
        if (nr > 0) doA(a0, nr);
        __syncthreads();
    }

    // ---- deterministic block reduction ----
    red[tid] = acc;
    __syncthreads();
    #pragma unroll
    for (int off = 128; off > 0; off >>= 1) {
        if (tid < off) red[tid] += red[tid + off];
        __syncthreads();
    }
    if (tid == 0) block_sums[blk] = red[0];
}

__global__ __launch_bounds__(256) void ssim_finalize_kernel(
    const float* __restrict__ block_sums,
    float* __restrict__ out,
    int nblk,
    float inv_npix)
{
    __shared__ float red[256];
    const int tid = threadIdx.x;
    float s = 0.f;
    for (int i = tid; i < nblk; i += 256) s += block_sums[i];
    red[tid] = s;
    __syncthreads();
    #pragma unroll
    for (int off = 128; off > 0; off >>= 1) {
        if (tid < off) red[tid] += red[tid + off];
        __syncthreads();
    }
    if (tid == 0) {
        const float mean = red[0] * inv_npix;
        out[0] = 5.0f * (1.0f - mean);
    }
}

extern "C" void kernel_launch(void* const* d_in, const int* in_sizes, int n_in,
                              void* d_out, int out_size, void* d_ws, size_t ws_size,
                              hipStream_t stream)
{
    const float* img  = (const float*)d_in[0];
    const float* imgr = (const float*)d_in[1];
    const int*   tgt  = (const int*)d_in[2];
    const int N = in_sizes[2] / 5;
    const int nblk = 3 * N;

    float* block_sums = (float*)d_ws;
    const float inv_npix = 1.0f / ((float)nblk * (float)(OUT * OUT));

    ssim_kernel<<<nblk, 256, 0, stream>>>(img, imgr, tgt, block_sums);
    ssim_finalize_kernel<<<1, 256, 0, stream>>>(block_sums, (float*)d_out, nblk, inv_npix);
}

// Round 6
// 34.173 us; speedup vs baseline: 9.6335x; 1.0274x over previous
//
#include <hip/hip_runtime.h>
#include <math.h>

#define CROP 96
#define WIN 11
#define OUT 86          // CROP - WIN + 1
#define IMH 1080
#define IMW 1920
#define NIT 11          // chunks of 8 output rows: 86 = 10*8 + 6
#define RSW 352         // words per row-slot: 88 x-positions * 4 floats
#define NSLOT 32        // circular row buffer (power of 2)

typedef float v2f __attribute__((ext_vector_type(2)));

// LDS: hbuf[slot][x 0..87][4] = (P, Q, PP, QQ) — horizontal 11-tap conv of
// p=a+b, q=a-b, p^2, q^2 for input row `slot`, out-col x.

__global__ __launch_bounds__(256) void ssim_kernel(
    const float* __restrict__ img,
    const float* __restrict__ imgr,
    const int* __restrict__ target,
    float* __restrict__ block_sums)
{
    __shared__ __align__(16) float hbuf[NSLOT * RSW];   // 45056 B
    __shared__ float red[256];

    const int blk = blockIdx.x;          // 0 .. 3N-1
    const int s   = blk / 3;
    const int c   = blk % 3;

    const int xmin = target[s * 5 + 0];
    const int ymin = target[s * 5 + 1];

    const size_t cbase = (size_t)c * (IMH * IMW) + (size_t)ymin * IMW + (size_t)xmin;
    const float* __restrict__ pa = img  + cbase;
    const float* __restrict__ pb = imgr + cbase;

    const int tid = threadIdx.x;

    // gaussian weights (f32, matches reference)
    float gw[WIN];
    {
        float sum = 0.f;
        #pragma unroll
        for (int k = 0; k < WIN; ++k) {
            const float cc = (float)k - (float)(WIN - 1) * 0.5f;
            gw[k] = expf(-(cc * cc) / (2.0f * 1.5f * 1.5f));
            sum += gw[k];
        }
        const float inv = 1.0f / sum;
        #pragma unroll
        for (int k = 0; k < WIN; ++k) gw[k] *= inv;
    }

    // ---- horizontal 11-tap conv of one input row, 12 out-cols, packed pairs ----
    auto doA_task = [&](int row, int g) {
        const int xo = (g == 7) ? 74 : 12 * g;         // window xo..xo+21 <= 95
        const float* __restrict__ ra = pa + (size_t)row * IMW + xo;
        const float* __restrict__ rb = pb + (size_t)row * IMW + xo;

        v2f aPQ[12] = {}; v2f aP2[12] = {};
        #pragma unroll
        for (int tt = 0; tt < 22; ++tt) {              // static offsets, no clamp
            const float a = ra[tt];
            const float b = rb[tt];
            const v2f pq  = {a + b, a - b};
            const v2f pq2 = pq * pq;
            #pragma unroll
            for (int jj = 0; jj < 12; ++jj) {
                const int kk = tt - jj;
                if (kk >= 0 && kk < WIN) {
                    aPQ[jj] += pq  * gw[kk];           // v_pk_fma_f32
                    aP2[jj] += pq2 * gw[kk];
                }
            }
        }
        const int sbase = (row & (NSLOT - 1)) * RSW;
        #pragma unroll
        for (int jj = 0; jj < 12; ++jj) {
            const int x = xo + jj;
            *(float4*)&hbuf[sbase + x * 4] =
                make_float4(aPQ[jj].x, aPQ[jj].y, aP2[jj].x, aP2[jj].y);
        }
    };

    // ---- prologue: fill input rows 0..17 (18 rows x 8 groups = 144 tasks) ----
    if (tid < 144) doA_task(tid >> 3, tid & 7);
    __syncthreads();

    const float C1 = 6.5025f;
    const float C2 = 58.5225f;
    float acc = 0.f;

    // hoisted per-thread task coordinates
    const int bx   = (tid < 172) ? (tid % 86) : 0;     // B: out-col
    const int bgrp = (tid < 172) ? (tid / 86) : 0;     // B: 4-row group 0/1
    const int au   = tid - 192;                        // A: 0..63 when tid>=192
    const int arow0 = (au >> 3) + 18;                  // A: row offset base
    const int ag    = au & 7;

    for (int k = 0; k < NIT; ++k) {
        const int r0out = 8 * k;

        if (tid < 172) {
            // ---- B: vertical 11-tap conv + SSIM, 4 out-rows x 1 col ----
            const int r0 = r0out + bgrp * 4;
            v2f mPQ[4] = {}; v2f mP2[4] = {};
            #pragma unroll
            for (int tt = 0; tt < 14; ++tt) {          // rows r0..r0+13 cover 4 out-rows
                const int slot = (r0 + tt) & (NSLOT - 1);
                const float4 f = *(const float4*)&hbuf[slot * RSW + bx * 4];
                const v2f fPQ = {f.x, f.y};
                const v2f fP2 = {f.z, f.w};
                #pragma unroll
                for (int jj = 0; jj < 4; ++jj) {
                    const int kk = tt - jj;
                    if (kk >= 0 && kk < WIN) {
                        mPQ[jj] += fPQ * gw[kk];       // v_pk_fma_f32
                        mP2[jj] += fP2 * gw[kk];
                    }
                }
            }
            #pragma unroll
            for (int jj = 0; jj < 4; ++jj) {
                if (r0 + jj < OUT) {
                    const v2f sq = mPQ[jj] * mPQ[jj];          // {P^2, Q^2}
                    const float mu12x2  = (sq.x - sq.y) * 0.5f;       // 2*mu1*mu2
                    const float musqsum = (sq.x + sq.y) * 0.5f;       // mu1^2+mu2^2
                    const float e_dif = (mP2[jj].x - mP2[jj].y) * 0.5f; // 2*E[ab]
                    const float e_sum = (mP2[jj].x + mP2[jj].y) * 0.5f; // E[a^2]+E[b^2]
                    const float s12x2 = e_dif - mu12x2;
                    const float ssum  = e_sum - musqsum;
                    const float num = (mu12x2 + C1) * (s12x2 + C2);
                    const float den = (musqsum + C1) * (ssum + C2);
                    acc += num * __builtin_amdgcn_rcpf(den);
                }
            }
        } else if (tid >= 192) {
            // ---- A: horizontal conv of next chunk's input rows ----
            const int row = r0out + arow0;             // 8k+18 .. 8k+25
            if (row < CROP) doA_task(row, ag);
        }
        __syncthreads();
    }

    // ---- deterministic block reduction ----
    red[tid] = acc;
    __syncthreads();
    #pragma unroll
    for (int off = 128; off > 0; off >>= 1) {
        if (tid < off) red[tid] += red[tid + off];
        __syncthreads();
    }
    if (tid == 0) block_sums[blk] = red[0];
}

__global__ __launch_bounds__(256) void ssim_finalize_kernel(
    const float* __restrict__ block_sums,
    float* __restrict__ out,
    int nblk,
    float inv_npix)
{
    __shared__ float red[256];
    const int tid = threadIdx.x;
    float s = 0.f;
    for (int i = tid; i < nblk; i += 256) s += block_sums[i];
    red[tid] = s;
    __syncthreads();
    #pragma unroll
    for (int off = 128; off > 0; off >>= 1) {
        if (tid < off) red[tid] += red[tid + off];
        __syncthreads();
    }
    if (tid == 0) {
        const float mean = red[0] * inv_npix;
        out[0] = 5.0f * (1.0f - mean);
    }
}

extern "C" void kernel_launch(void* const* d_in, const int* in_sizes, int n_in,
                              void* d_out, int out_size, void* d_ws, size_t ws_size,
                              hipStream_t stream)
{
    const float* img  = (const float*)d_in[0];
    const float* imgr = (const float*)d_in[1];
    const int*   tgt  = (const int*)d_in[2];
    const int N = in_sizes[2] / 5;
    const int nblk = 3 * N;

    float* block_sums = (float*)d_ws;
    const float inv_npix = 1.0f / ((float)nblk * (float)(OUT * OUT));

    ssim_kernel<<<nblk, 256, 0, stream>>>(img, imgr, tgt, block_sums);
    ssim_finalize_kernel<<<1, 256, 0, stream>>>(block_sums, (float*)d_out, nblk, inv_npix);
}